// Round 3
// baseline (153.374 us; speedup 1.0000x reference)
//
#include <hip/hip_runtime.h>
#include <math.h>

// Problem constants
#define BB 16      // batch
#define LL 32      // L
#define AA 2046    // attributor cols
#define MM 2048    // M = A + 2
#define NROWS 192  // 6L

// Workspace layout (floats):
//   uv[4][16][64]    u0,u1,v0,v1  (4096)
//   c [2][16][2048]  c0,c1        (65536)

// ---------------------------------------------------------------------------
// Kernel 0: per-batch prep (tiny).
//   K0[l] = sum_{r=64..127} relu(user[b,r]) W2[r,l]   (Key col 0)
//   K1[l] = sum_{r=64..127} relu(item[b,r]) W2[r,l]   (Key col M-1)
//   Q0[l] = sum_{r=0..63}   relu(user[b,r]) W2[r,l]   (Query col 0)
//   Q1[l] = sum_{r=0..63}   relu(item[b,r]) W2[r,l]
//   u0[b,r] = sum_l W2[r,l]·K0[l]      (r in [0,64)  -> weights for s0)
//   u1[b,r] = sum_l W2[r,l]·K1[l]
//   v0[b,r] = sum_l W2[64+r,l]·Q0[l]   (weights for t0)
//   v1[b,r] = sum_l W2[64+r,l]·Q1[l]
// ---------------------------------------------------------------------------
__global__ __launch_bounds__(256) void prep_kernel(
    const float* __restrict__ user, const float* __restrict__ item,
    const float* __restrict__ W2, float* __restrict__ uv) {
  const int b = blockIdx.x, t = threadIdx.x;
  __shared__ float KQ[4][LL];
  if (t < 128) {
    const int q = t >> 5, l = t & 31;
    const float* __restrict__ src = (q == 0 || q == 2) ? user : item;
    const int rbase = (q < 2) ? 64 : 0;
    float acc = 0.f;
#pragma unroll
    for (int r = 0; r < 64; ++r)
      acc += fmaxf(src[b * NROWS + rbase + r], 0.f) * W2[(rbase + r) * LL + l];
    KQ[q][l] = acc;
  }
  __syncthreads();
  const int which = t >> 6, r = t & 63;
  const int wrow = (which < 2) ? r : 64 + r;
  float acc = 0.f;
#pragma unroll
  for (int l = 0; l < LL; ++l) acc += W2[wrow * LL + l] * KQ[which][l];
  uv[which * (BB * 64) + b * 64 + r] = acc;
}

// ---------------------------------------------------------------------------
// Kernel 1 (fused s/t + causal weight): one thread owns one (b,n).
//   s0 = sum_{r<64}    relu(raw[b,r,n])·u0[b,r]   (s1 with u1)
//   t0 = sum_{r=64..127} relu(raw[b,r,n])·v0[b,r-64] (t1 with v1)
//   d0 = s0·adj[n,0]·iw[n,0] − t0·adj[0,n]·iw[0,n]
//   c0 = sigmoid(d0)·adj[n,0]   (stable sigmoid == exp(min(d,0))/(e+e^T) form)
// raw[b,r,0]=user, raw[b,r,M-1]=item, else att·W1. Coalesced over n.
// grid (16 ntiles, 16 b) = 256 blocks × 128 threads.
// ---------------------------------------------------------------------------
__global__ __launch_bounds__(128) void stc_kernel(
    const float* __restrict__ user, const float* __restrict__ item,
    const float* __restrict__ att, const float* __restrict__ W1,
    const float* __restrict__ uv, const float* __restrict__ adj,
    const float* __restrict__ iw, float* __restrict__ c) {
  const int n = blockIdx.x * 128 + threadIdx.x;
  const int b = blockIdx.y;
  const float* __restrict__ u0 = uv + 0 * (BB * 64) + b * 64;  // uniform
  const float* __restrict__ u1 = uv + 1 * (BB * 64) + b * 64;
  const float* __restrict__ v0 = uv + 2 * (BB * 64) + b * 64;
  const float* __restrict__ v1 = uv + 3 * (BB * 64) + b * 64;

  const bool isU = (n == 0), isI = (n == MM - 1);
  const int col = (isU || isI) ? 0 : (n - 1);  // clamped: keeps address valid

  float s0 = 0.f, s1 = 0.f, t0 = 0.f, t1 = 0.f;
#pragma unroll 16
  for (int r = 0; r < 64; ++r) {
    const int gr = b * NROWS + r;
    float v = isU ? user[gr]
                  : (isI ? item[gr]
                         : att[(size_t)gr * AA + col] *
                               W1[(size_t)r * AA + col]);
    v = fmaxf(v, 0.f);
    s0 += v * u0[r];
    s1 += v * u1[r];
  }
#pragma unroll 16
  for (int r = 64; r < 128; ++r) {
    const int gr = b * NROWS + r;
    float v = isU ? user[gr]
                  : (isI ? item[gr]
                         : att[(size_t)gr * AA + col] *
                               W1[(size_t)r * AA + col]);
    v = fmaxf(v, 0.f);
    t0 += v * v0[r - 64];
    t1 += v * v1[r - 64];
  }

  const float an0 = adj[(size_t)n * MM];
  const float an1 = adj[(size_t)n * MM + (MM - 1)];
  const float wn0 = an0 * iw[(size_t)n * MM];
  const float wn1 = an1 * iw[(size_t)n * MM + (MM - 1)];
  const float w0n = adj[n] * iw[n];                             // row 0
  const float w1n =
      adj[(size_t)(MM - 1) * MM + n] * iw[(size_t)(MM - 1) * MM + n];

  const float d0 = s0 * wn0 - t0 * w0n;
  const float d1 = s1 * wn1 - t1 * w1n;
  const float e0 = expf(-fabsf(d0));
  const float e1 = expf(-fabsf(d1));
  const float sig0 = (d0 > 0.f) ? 1.f / (1.f + e0) : e0 / (1.f + e0);
  const float sig1 = (d1 > 0.f) ? 1.f / (1.f + e1) : e1 / (1.f + e1);

  c[b * MM + n] = sig0 * an0;
  c[BB * MM + b * MM + n] = sig1 * an1;
}

// ---------------------------------------------------------------------------
// Kernel 2: g_j[b,r] = sum_n relu(raw[b,128+rv,n])·c_j[b,n], then
//   out[b,l,j] += W2[128+rv,l]·g_j  (atomic).
// grid (64 rv, 16 b) = 1024 blocks × 256 threads, 8 coalesced n/thread.
// ---------------------------------------------------------------------------
__global__ __launch_bounds__(256) void gather_kernel(
    const float* __restrict__ user, const float* __restrict__ item,
    const float* __restrict__ att, const float* __restrict__ W1,
    const float* __restrict__ c, const float* __restrict__ W2,
    float* __restrict__ out) {
  const int rv = blockIdx.x, b = blockIdx.y, tid = threadIdx.x;
  const int r = 128 + rv;
  const int gr = b * NROWS + r;
  const float uval = fmaxf(user[gr], 0.f);
  const float ival = fmaxf(item[gr], 0.f);
  const float* __restrict__ c0 = c + b * MM;
  const float* __restrict__ c1 = c + BB * MM + b * MM;
  float g0 = 0.f, g1 = 0.f;
#pragma unroll
  for (int i = 0; i < 8; ++i) {
    const int n = i * 256 + tid;
    const bool isU = (n == 0), isI = (n == MM - 1);
    const int col = (isU || isI) ? 0 : (n - 1);
    float v = isU ? uval
                  : (isI ? ival
                         : fmaxf(att[(size_t)gr * AA + col] *
                                     W1[(size_t)r * AA + col],
                                 0.f));
    g0 += v * c0[n];
    g1 += v * c1[n];
  }
  __shared__ float r0[256], r1[256];
  r0[tid] = g0;
  r1[tid] = g1;
  __syncthreads();
  for (int s = 128; s > 0; s >>= 1) {
    if (tid < s) {
      r0[tid] += r0[tid + s];
      r1[tid] += r1[tid + s];
    }
    __syncthreads();
  }
  if (tid < 64) {
    const int l = tid & 31, j = tid >> 5;
    const float g = j ? r1[0] : r0[0];
    atomicAdd(&out[b * (LL * 2) + l * 2 + j], W2[r * LL + l] * g);
  }
}

extern "C" void kernel_launch(void* const* d_in, const int* in_sizes, int n_in,
                              void* d_out, int out_size, void* d_ws,
                              size_t ws_size, hipStream_t stream) {
  const float* user = (const float*)d_in[0];
  const float* item = (const float*)d_in[1];
  const float* att = (const float*)d_in[2];
  const float* adj = (const float*)d_in[3];
  const float* iw = (const float*)d_in[4];
  const float* W1 = (const float*)d_in[5];
  const float* W2 = (const float*)d_in[6];
  float* out = (float*)d_out;

  float* uv = (float*)d_ws;       // 4096 floats
  float* c = uv + 4 * BB * 64;    // 65536 floats

  hipMemsetAsync(d_out, 0, sizeof(float) * (size_t)out_size, stream);

  prep_kernel<<<dim3(BB), 256, 0, stream>>>(user, item, W2, uv);
  stc_kernel<<<dim3(MM / 128, BB), 128, 0, stream>>>(user, item, att, W1, uv,
                                                     adj, iw, c);
  gather_kernel<<<dim3(64, BB), 256, 0, stream>>>(user, item, att, W1, c, W2,
                                                  out);
}

// Round 4
// 112.739 us; speedup vs baseline: 1.3604x; 1.3604x over previous
//
#include <hip/hip_runtime.h>
#include <math.h>

// Problem constants
#define BB 16      // batch
#define LL 32      // L
#define AA 2046    // attributor cols
#define MM 2048    // M = A + 2
#define NROWS 192  // 6L

// Workspace layout (floats):
//   uv  [4][16][64]      u0,u1,v0,v1                  (4096)
//   part[4][2][16][2048] r-chunk partials of s/t      (262144)
//   c   [2][16][2048]    c0,c1                        (65536)

__device__ __forceinline__ size_t Pidx(int rc, int j, int b, int n) {
  return ((size_t)(rc * 2 + j) * BB + b) * MM + n;
}

// ---------------------------------------------------------------------------
// Kernel 0: per-batch prep (tiny, 16 blocks).
// Stage 1: K0/K1/Q0/Q1[l] projections of user/item columns.
// Stage 2: u_j[r] = W2[r,:]·K_j   (weights for s_j, r in [0,64))
//          v_j[r] = W2[64+r,:]·Q_j (weights for t_j)
// Stage 3: boundary columns n=0 (user) and n=M-1 (item):
//          s_j(n) = sum_{r<64} relu(src[b,r])·u_j[r]
//          t_j(n) = sum_{r=64..127} relu(src[b,r])·v_j[r-64]
//          written into part[] so cweight needs no special cases.
// ---------------------------------------------------------------------------
__global__ __launch_bounds__(256) void prep_kernel(
    const float* __restrict__ user, const float* __restrict__ item,
    const float* __restrict__ W2, float* __restrict__ uv,
    float* __restrict__ part) {
  const int b = blockIdx.x, t = threadIdx.x;
  __shared__ float KQ[4][LL];
  __shared__ float uvs[4][64];
  if (t < 128) {
    const int q = t >> 5, l = t & 31;
    const float* __restrict__ src = (q == 0 || q == 2) ? user : item;
    const int rbase = (q < 2) ? 64 : 0;  // K from rows 64..127, Q from 0..63
    float acc = 0.f;
#pragma unroll
    for (int r = 0; r < 64; ++r)
      acc += fmaxf(src[b * NROWS + rbase + r], 0.f) * W2[(rbase + r) * LL + l];
    KQ[q][l] = acc;  // 0:K0(user) 1:K1(item) 2:Q0(user) 3:Q1(item)
  }
  __syncthreads();
  {
    const int which = t >> 6, r = t & 63;
    const int wrow = (which < 2) ? r : 64 + r;
    float acc = 0.f;
#pragma unroll
    for (int l = 0; l < LL; ++l) acc += W2[wrow * LL + l] * KQ[which][l];
    uvs[which][r] = acc;
    uv[which * (BB * 64) + b * 64 + r] = acc;
  }
  __syncthreads();
  if (t < 8) {
    const int nsel = t & 1, j = (t >> 1) & 1, z = t >> 2;
    const float* __restrict__ src = nsel ? item : user;
    float acc = 0.f;
#pragma unroll
    for (int i = 0; i < 64; ++i)
      acc += fmaxf(src[b * NROWS + z * 64 + i], 0.f) * uvs[2 * z + j][i];
    const int n = nsel ? (MM - 1) : 0;
    part[Pidx(2 * z, j, b, n)] = acc;
    part[Pidx(2 * z + 1, j, b, n)] = 0.f;
  }
}

// ---------------------------------------------------------------------------
// Kernel 1: s/t partial dot-products over interior columns, branch-free.
//   rc 0,1: s-partials over r in [rc*32, rc*32+32) with weights u0/u1
//   rc 2,3: t-partials with weights v0/v1 (index r-64)
// grid (8 coltiles, 16 b, 4 rc) = 512 blocks x 256 threads, coalesced.
// ---------------------------------------------------------------------------
__global__ __launch_bounds__(256) void st_kernel(
    const float* __restrict__ att, const float* __restrict__ W1,
    const float* __restrict__ uv, float* __restrict__ part) {
  const int col = blockIdx.x * 256 + threadIdx.x;
  const int b = blockIdx.y, rc = blockIdx.z;
  if (col >= AA) return;
  const int z = rc >> 1;
  const float* __restrict__ w0 = uv + (2 * z) * (BB * 64) + b * 64;
  const float* __restrict__ w1 = uv + (2 * z + 1) * (BB * 64) + b * 64;
  const int r0 = rc * 32;
  float a0 = 0.f, a1 = 0.f;
#pragma unroll
  for (int i = 0; i < 32; ++i) {
    const int r = r0 + i;
    const float v =
        fmaxf(att[(size_t)(b * NROWS + r) * AA + col] * W1[(size_t)r * AA + col],
              0.f);
    const int wi = r - z * 64;
    a0 += v * w0[wi];
    a1 += v * w1[wi];
  }
  const int n = col + 1;
  part[Pidx(rc, 0, b, n)] = a0;
  part[Pidx(rc, 1, b, n)] = a1;
}

// ---------------------------------------------------------------------------
// Kernel 2: combine partials -> causal weights for target cols {0, M-1}.
//   d0 = s0·adj[n,0]·iw[n,0] − t0·adj[0,n]·iw[0,n];  c0 = sigmoid(d0)·adj[n,0]
// (stable sigmoid == exp(min(d,0))/(exp(min(d,0))+exp(min(−d,0))))
// ---------------------------------------------------------------------------
__global__ __launch_bounds__(256) void cweight_kernel(
    const float* __restrict__ adj, const float* __restrict__ iw,
    const float* __restrict__ part, float* __restrict__ c) {
  const int idx = blockIdx.x * 256 + threadIdx.x;  // 16*2048
  const int b = idx >> 11, n = idx & (MM - 1);
  const float s0 = part[Pidx(0, 0, b, n)] + part[Pidx(1, 0, b, n)];
  const float s1 = part[Pidx(0, 1, b, n)] + part[Pidx(1, 1, b, n)];
  const float t0 = part[Pidx(2, 0, b, n)] + part[Pidx(3, 0, b, n)];
  const float t1 = part[Pidx(2, 1, b, n)] + part[Pidx(3, 1, b, n)];
  const float an0 = adj[(size_t)n * MM];
  const float an1 = adj[(size_t)n * MM + (MM - 1)];
  const float wn0 = an0 * iw[(size_t)n * MM];
  const float wn1 = an1 * iw[(size_t)n * MM + (MM - 1)];
  const float w0n = adj[n] * iw[n];
  const float w1n =
      adj[(size_t)(MM - 1) * MM + n] * iw[(size_t)(MM - 1) * MM + n];
  const float d0 = s0 * wn0 - t0 * w0n;
  const float d1 = s1 * wn1 - t1 * w1n;
  const float e0 = expf(-fabsf(d0));
  const float e1 = expf(-fabsf(d1));
  const float sig0 = (d0 > 0.f) ? 1.f / (1.f + e0) : e0 / (1.f + e0);
  const float sig1 = (d1 > 0.f) ? 1.f / (1.f + e1) : e1 / (1.f + e1);
  c[b * MM + n] = sig0 * an0;
  c[BB * MM + b * MM + n] = sig1 * an1;
}

// ---------------------------------------------------------------------------
// Kernel 3: g_j[b,r] = sum_n relu(raw[b,128+rv,n])·c_j[b,n], then
//   out[b,l,j] += W2[128+rv,l]·g_j  (atomic). Branch-free interior loop;
//   boundary (n=0 user, n=M-1 item) added by tid 0.
// grid (64 rv, 16 b) = 1024 blocks x 256 threads, coalesced.
// ---------------------------------------------------------------------------
__global__ __launch_bounds__(256) void gather_kernel(
    const float* __restrict__ user, const float* __restrict__ item,
    const float* __restrict__ att, const float* __restrict__ W1,
    const float* __restrict__ c, const float* __restrict__ W2,
    float* __restrict__ out) {
  const int rv = blockIdx.x, b = blockIdx.y, tid = threadIdx.x;
  const int r = 128 + rv;
  const int gr = b * NROWS + r;
  const float* __restrict__ c0 = c + b * MM;
  const float* __restrict__ c1 = c + BB * MM + b * MM;
  float g0 = 0.f, g1 = 0.f;
#pragma unroll
  for (int i = 0; i < 8; ++i) {
    const int col = i * 256 + tid;
    if (col < AA) {
      const float v = fmaxf(
          att[(size_t)gr * AA + col] * W1[(size_t)r * AA + col], 0.f);
      g0 += v * c0[col + 1];
      g1 += v * c1[col + 1];
    }
  }
  if (tid == 0) {
    const float uval = fmaxf(user[gr], 0.f);
    const float ival = fmaxf(item[gr], 0.f);
    g0 += uval * c0[0] + ival * c0[MM - 1];
    g1 += uval * c1[0] + ival * c1[MM - 1];
  }
  __shared__ float r0[256], r1[256];
  r0[tid] = g0;
  r1[tid] = g1;
  __syncthreads();
  for (int s = 128; s > 0; s >>= 1) {
    if (tid < s) {
      r0[tid] += r0[tid + s];
      r1[tid] += r1[tid + s];
    }
    __syncthreads();
  }
  if (tid < 64) {
    const int l = tid & 31, j = tid >> 5;
    const float g = j ? r1[0] : r0[0];
    atomicAdd(&out[b * (LL * 2) + l * 2 + j], W2[r * LL + l] * g);
  }
}

extern "C" void kernel_launch(void* const* d_in, const int* in_sizes, int n_in,
                              void* d_out, int out_size, void* d_ws,
                              size_t ws_size, hipStream_t stream) {
  const float* user = (const float*)d_in[0];
  const float* item = (const float*)d_in[1];
  const float* att = (const float*)d_in[2];
  const float* adj = (const float*)d_in[3];
  const float* iw = (const float*)d_in[4];
  const float* W1 = (const float*)d_in[5];
  const float* W2 = (const float*)d_in[6];
  float* out = (float*)d_out;

  float* uv = (float*)d_ws;            // 4096 floats
  float* part = uv + 4 * BB * 64;      // 262144 floats
  float* c = part + 8 * BB * MM;       // 65536 floats

  hipMemsetAsync(d_out, 0, sizeof(float) * (size_t)out_size, stream);

  prep_kernel<<<dim3(BB), 256, 0, stream>>>(user, item, W2, uv, part);
  st_kernel<<<dim3(8, BB, 4), 256, 0, stream>>>(att, W1, uv, part);
  cweight_kernel<<<dim3(BB * MM / 256), 256, 0, stream>>>(adj, iw, part, c);
  gather_kernel<<<dim3(64, BB), 256, 0, stream>>>(user, item, att, W1, c, W2,
                                                  out);
}